// Round 2
// baseline (41751.926 us; speedup 1.0000x reference)
//
#include <hip/hip_runtime.h>
#include <hip/hip_bf16.h>

// Inputs/outputs are FLOAT32 (per reference). Compute uses bf16 MFMA.
typedef __attribute__((ext_vector_type(8))) short short8;   // 8 bf16 = 4 VGPRs (MFMA A/B frag)
typedef __attribute__((ext_vector_type(4))) float floatx4;  // MFMA C/D frag

#define TBH ((size_t)16777216)  // 32768*512 per-gate G stride (elements)

__device__ __forceinline__ float bfbits2f(unsigned short b) {
  return __uint_as_float(((unsigned int)b) << 16);
}
__device__ __forceinline__ unsigned short f2bf(float f) {
  unsigned int u = __float_as_uint(f);
  unsigned int r = (u + 0x7fffu + ((u >> 16) & 1u)) >> 16;  // RNE
  return (unsigned short)r;
}

// -------------------------------------------------------------------------
// prep: h0 (f32) -> hbuf[0] (f32); zero 8192 flag ints; convert Whr/Whi/Whn
// to bf16 (Whb, 3*262144 elems).
// -------------------------------------------------------------------------
__global__ void prep_kernel(const float* __restrict__ h0,
                            float* __restrict__ hbuf0,
                            int* __restrict__ flags,
                            const float* __restrict__ Whr,
                            const float* __restrict__ Whi,
                            const float* __restrict__ Whn,
                            unsigned short* __restrict__ Whb) {
  int i = blockIdx.x * 256 + threadIdx.x;  // grid 1024*256 = 262144
  if (i < 64 * 512) hbuf0[i] = h0[i];
  if (i < 8192) flags[i] = 0;
#pragma unroll
  for (int rep = 0; rep < 3; ++rep) {
    int j = i + rep * 262144;
    float v = (j < 262144) ? Whr[j] : ((j < 524288) ? Whi[j - 262144] : Whn[j - 524288]);
    Whb[j] = f2bf(v);
  }
}

// -------------------------------------------------------------------------
// Phase 1: G[gate][t*64+b][n] = x@Wi^T + ctx@Wp^T + (bi+bh+bp)   (bf16 out)
// 128x128 tile, BK=32; f32 global -> bf16 LDS staging; 4 waves each 64x64.
// -------------------------------------------------------------------------
struct PreArgs {
  const float* x;
  const float* ctx;
  const float* Wi[3];
  const float* Wp[3];
  const float* bi[3];
  const float* bh[3];
  const float* bp[3];
  unsigned short* G;
};

__global__ __launch_bounds__(256) void gemm_pre(PreArgs args) {
  __shared__ short8 a_sm[512];  // [row(128)][sub(4)] : 128x32 bf16
  __shared__ short8 b_sm[512];
  const int tid = threadIdx.x;
  const int gate = blockIdx.z;
  const int n0 = blockIdx.x * 128;
  const int m0 = blockIdx.y * 128;
  const int wave = tid >> 6, lane = tid & 63;
  const int wm = (wave & 1) * 64, wn = (wave >> 1) * 64;
  const int lm = lane & 15, lq = lane >> 4;
  const float* Wi = args.Wi[gate];
  const float* Wp = args.Wp[gate];

  floatx4 acc[4][4];
#pragma unroll
  for (int i = 0; i < 4; ++i)
#pragma unroll
    for (int j = 0; j < 4; ++j) acc[i][j] = floatx4{0.f, 0.f, 0.f, 0.f};

  for (int kb = 0; kb < 32; ++kb) {
    const float* asrc = (kb < 16) ? args.x : args.ctx;
    const float* bsrc = (kb < 16) ? Wi : Wp;
    const int k0 = (kb & 15) * 32;
    __syncthreads();
#pragma unroll
    for (int c = 0; c < 2; ++c) {
      int s = c * 256 + tid;
      int row = s >> 2, sub = s & 3;
      const float* ap = asrc + (size_t)(m0 + row) * 512 + k0 + sub * 8;
      const float* bp = bsrc + (size_t)(n0 + row) * 512 + k0 + sub * 8;
      float4 a0 = *(const float4*)ap, a1 = *(const float4*)(ap + 4);
      float4 b0 = *(const float4*)bp, b1 = *(const float4*)(bp + 4);
      short8 av, bv;
      av[0] = (short)f2bf(a0.x); av[1] = (short)f2bf(a0.y);
      av[2] = (short)f2bf(a0.z); av[3] = (short)f2bf(a0.w);
      av[4] = (short)f2bf(a1.x); av[5] = (short)f2bf(a1.y);
      av[6] = (short)f2bf(a1.z); av[7] = (short)f2bf(a1.w);
      bv[0] = (short)f2bf(b0.x); bv[1] = (short)f2bf(b0.y);
      bv[2] = (short)f2bf(b0.z); bv[3] = (short)f2bf(b0.w);
      bv[4] = (short)f2bf(b1.x); bv[5] = (short)f2bf(b1.y);
      bv[6] = (short)f2bf(b1.z); bv[7] = (short)f2bf(b1.w);
      a_sm[row * 4 + sub] = av;
      b_sm[row * 4 + sub] = bv;
    }
    __syncthreads();
    short8 af[4], bf[4];
#pragma unroll
    for (int i = 0; i < 4; ++i) af[i] = a_sm[(wm + i * 16 + lm) * 4 + lq];
#pragma unroll
    for (int j = 0; j < 4; ++j) bf[j] = b_sm[(wn + j * 16 + lm) * 4 + lq];
#pragma unroll
    for (int i = 0; i < 4; ++i)
#pragma unroll
      for (int j = 0; j < 4; ++j)
        acc[i][j] = __builtin_amdgcn_mfma_f32_16x16x32_bf16(af[i], bf[j], acc[i][j], 0, 0, 0);
  }

  // epilogue: C/D layout col=lane&15, row=(lane>>4)*4+reg  [verified m89]
#pragma unroll
  for (int j = 0; j < 4; ++j) {
    int n = n0 + wn + j * 16 + lm;
    float bias = args.bi[gate][n] + args.bh[gate][n] + args.bp[gate][n];
#pragma unroll
    for (int i = 0; i < 4; ++i) {
      int mbase = m0 + wm + i * 16 + lq * 4;
#pragma unroll
      for (int r = 0; r < 4; ++r) {
        int m = mbase + r;            // m = b*512 + t (x row-major [B,T,D])
        int t = m & 511, b = m >> 9;  // G row = t*64 + b
        args.G[(size_t)gate * TBH + (size_t)(t * 64 + b) * 512 + n] = f2bf(acc[i][j][r] + bias);
      }
    }
  }
}

// -------------------------------------------------------------------------
// Recurrence: 256 persistent WGs = 8 batch-groups (8 batches) x 32 col-blocks
// (16 cols). W_h slice LDS-resident in fragment-packed layout. Two flag
// syncs per step (r/i publish -> n needs full r*h; then hy publish).
// -------------------------------------------------------------------------
__global__ __launch_bounds__(256, 1) void recur_kernel(
    const unsigned short* __restrict__ G,
    const unsigned short* __restrict__ Whb,  // [3][512][512] bf16
    float* __restrict__ hbuf,                // [2][64][512] f32 (double-buffered h)
    unsigned short* __restrict__ rhpub,      // [64][512] bf16
    unsigned short* __restrict__ ipub,       // [64][512] bf16
    int* __restrict__ flagA, int* __restrict__ flagB,  // [8][512]
    float* __restrict__ ys,                  // [64][512][512] f32
    float* __restrict__ hT) {                // [64][512] f32
  __shared__ short8 w_sm[3 * 16 * 64];  // [gate][kb][lane] frag-packed: 48 KB
  __shared__ short8 hp_sm[16 * 64];     // h (phase A) then r*h (phase B): 16 KB

  const int tid = threadIdx.x;
  const int g = blockIdx.x & 7;    // batch group
  const int cb = blockIdx.x >> 3;  // col block 0..31
  const int b0 = g * 8;
  const int c0 = cb * 16;
  const int wave = tid >> 6, lane = tid & 63;
  const int lm = lane & 15, lq = lane >> 4;

  // ---- load weight slices once, fragment-packed (lane-sequential 16B) ----
#pragma unroll
  for (int gate = 0; gate < 3; ++gate) {
    const unsigned short* W = Whb + (size_t)gate * 262144;
    for (int s = tid; s < 1024; s += 256) {  // kb*64 + l
      int kb = s >> 6, l = s & 63;
      w_sm[gate * 1024 + s] =
          *(const short8*)(W + (size_t)(c0 + (l & 15)) * 512 + kb * 32 + (l >> 4) * 8);
    }
  }
  __syncthreads();

  for (int t = 0; t < 512; ++t) {
    const float* h_in = hbuf + (size_t)(t & 1) * (64 * 512);
    float* h_out = hbuf + (size_t)((t + 1) & 1) * (64 * 512);

    // ---- stage h (f32 global -> bf16 frag-packed LDS); rows 8..15 = zero pad
    for (int s = tid; s < 1024; s += 256) {
      int l = s & 63;
      int m = l & 15;
      short8 v = {0, 0, 0, 0, 0, 0, 0, 0};
      if (m < 8) {
        const float* src = h_in + (size_t)(b0 + m) * 512 + (s >> 6) * 32 + (l >> 4) * 8;
#pragma unroll
        for (int j = 0; j < 8; ++j) v[j] = (short)f2bf(src[j]);
      }
      hp_sm[s] = v;
    }
    __syncthreads();

    // ---- phase A: wave0 -> r gate, wave1 -> i gate ----
    if (wave < 2) {
      const int gate = wave;
      float gv[4], hvv[4];
#pragma unroll
      for (int r = 0; r < 4; ++r) {
        int b = lq * 4 + r;
        if (b < 8) {
          int gb = b0 + b, col = c0 + lm;
          gv[r] = bfbits2f(G[(size_t)gate * TBH + (size_t)(t * 64 + gb) * 512 + col]);
          hvv[r] = h_in[(size_t)gb * 512 + col];
        } else {
          gv[r] = 0.f;
          hvv[r] = 0.f;
        }
      }
      floatx4 acc = {0.f, 0.f, 0.f, 0.f};
#pragma unroll
      for (int kb = 0; kb < 16; ++kb)
        acc = __builtin_amdgcn_mfma_f32_16x16x32_bf16(hp_sm[kb * 64 + lane],
                                                      w_sm[(gate * 16 + kb) * 64 + lane],
                                                      acc, 0, 0, 0);
#pragma unroll
      for (int r = 0; r < 4; ++r) {
        int b = lq * 4 + r;
        if (b < 8) {
          int gb = b0 + b, col = c0 + lm;
          float pre = acc[r] + gv[r];
          float sv = 1.f / (1.f + __expf(-pre));
          if (gate == 0)
            rhpub[(size_t)gb * 512 + col] = f2bf(sv * hvv[r]);  // r * h
          else
            ipub[(size_t)gb * 512 + col] = f2bf(sv);  // i
        }
      }
    }
    __threadfence();
    __syncthreads();
    if (tid == 0) {
      __hip_atomic_fetch_add(&flagA[g * 512 + t], 1, __ATOMIC_RELEASE, __HIP_MEMORY_SCOPE_AGENT);
      while (__hip_atomic_load(&flagA[g * 512 + t], __ATOMIC_ACQUIRE, __HIP_MEMORY_SCOPE_AGENT) < 32)
        __builtin_amdgcn_s_sleep(1);
    }
    __syncthreads();
    __threadfence();

    // ---- stage r*h (bf16 global -> frag-packed LDS, overwrites h) ----
    for (int s = tid; s < 1024; s += 256) {
      int l = s & 63;
      int m = l & 15;
      short8 v = {0, 0, 0, 0, 0, 0, 0, 0};
      if (m < 8)
        v = *(const short8*)(rhpub + (size_t)(b0 + m) * 512 + (s >> 6) * 32 + (l >> 4) * 8);
      hp_sm[s] = v;
    }
    __syncthreads();

    // ---- phase B: wave0 -> n gate + hy ----
    if (wave == 0) {
      float gv[4], hvv[4], iv[4];
#pragma unroll
      for (int r = 0; r < 4; ++r) {
        int b = lq * 4 + r;
        if (b < 8) {
          int gb = b0 + b, col = c0 + lm;
          gv[r] = bfbits2f(G[2 * TBH + (size_t)(t * 64 + gb) * 512 + col]);
          hvv[r] = h_in[(size_t)gb * 512 + col];
          iv[r] = bfbits2f(ipub[(size_t)gb * 512 + col]);
        } else {
          gv[r] = 0.f; hvv[r] = 0.f; iv[r] = 0.f;
        }
      }
      floatx4 acc = {0.f, 0.f, 0.f, 0.f};
#pragma unroll
      for (int kb = 0; kb < 16; ++kb)
        acc = __builtin_amdgcn_mfma_f32_16x16x32_bf16(hp_sm[kb * 64 + lane],
                                                      w_sm[(2 * 16 + kb) * 64 + lane],
                                                      acc, 0, 0, 0);
#pragma unroll
      for (int r = 0; r < 4; ++r) {
        int b = lq * 4 + r;
        if (b < 8) {
          int gb = b0 + b, col = c0 + lm;
          float pre = acc[r] + gv[r];
          float e = __expf(2.f * pre);
          float nv = 1.f - 2.f / (e + 1.f);  // tanh
          float hy = (1.f - iv[r]) * hvv[r] + iv[r] * nv;
          h_out[(size_t)gb * 512 + col] = hy;
          ys[((size_t)gb * 512 + (size_t)t) * 512 + col] = hy;
          if (t == 511) hT[(size_t)gb * 512 + col] = hy;
        }
      }
    }
    __threadfence();
    __syncthreads();
    if (tid == 0) {
      __hip_atomic_fetch_add(&flagB[g * 512 + t], 1, __ATOMIC_RELEASE, __HIP_MEMORY_SCOPE_AGENT);
      while (__hip_atomic_load(&flagB[g * 512 + t], __ATOMIC_ACQUIRE, __HIP_MEMORY_SCOPE_AGENT) < 32)
        __builtin_amdgcn_s_sleep(1);
    }
    __syncthreads();
    __threadfence();
  }
}

// -------------------------------------------------------------------------
extern "C" void kernel_launch(void* const* d_in, const int* in_sizes, int n_in,
                              void* d_out, int out_size, void* d_ws, size_t ws_size,
                              hipStream_t stream) {
  typedef const float* cfp;
  cfp x = (cfp)d_in[0];
  cfp h0 = (cfp)d_in[1];
  cfp ctx = (cfp)d_in[2];

  PreArgs pa;
  pa.x = x;
  pa.ctx = ctx;
  for (int gi = 0; gi < 3; ++gi) {
    pa.Wi[gi] = (cfp)d_in[3 + 6 * gi];
    pa.bi[gi] = (cfp)d_in[4 + 6 * gi];
    pa.bh[gi] = (cfp)d_in[6 + 6 * gi];
    pa.Wp[gi] = (cfp)d_in[7 + 6 * gi];
    pa.bp[gi] = (cfp)d_in[8 + 6 * gi];
  }
  cfp Whr = (cfp)d_in[5], Whi = (cfp)d_in[11], Whn = (cfp)d_in[17];

  char* ws = (char*)d_ws;
  unsigned short* G = (unsigned short*)ws;          // 3 gates x 32 MB bf16
  size_t off = (size_t)3 * TBH * 2;                 // 100,663,296 B
  unsigned short* Whb = (unsigned short*)(ws + off);
  off += (size_t)3 * 262144 * 2;                    // 1,572,864 B
  float* hbuf = (float*)(ws + off);
  off += (size_t)2 * 64 * 512 * 4;
  unsigned short* rhpub = (unsigned short*)(ws + off);
  off += (size_t)64 * 512 * 2;
  unsigned short* ipub = (unsigned short*)(ws + off);
  off += (size_t)64 * 512 * 2;
  int* flagA = (int*)(ws + off);
  off += (size_t)4096 * 4;
  int* flagB = (int*)(ws + off);
  off += (size_t)4096 * 4;
  pa.G = G;

  float* out = (float*)d_out;
  float* ys = out;
  float* hT = out + (size_t)64 * 512 * 512;

  prep_kernel<<<1024, 256, 0, stream>>>(h0, hbuf, flagA, Whr, Whi, Whn, Whb);
  dim3 gp(4, 256, 3);
  gemm_pre<<<gp, 256, 0, stream>>>(pa);
  recur_kernel<<<256, 256, 0, stream>>>(G, Whb, hbuf, rhpub, ipub, flagA, flagB, ys, hT);
}

// Round 3
// 5726.967 us; speedup vs baseline: 7.2904x; 7.2904x over previous
//
#include <hip/hip_runtime.h>
#include <hip/hip_bf16.h>

// Inputs/outputs are FLOAT32 (per reference). Compute uses bf16 MFMA.
typedef __attribute__((ext_vector_type(8))) short short8;   // 8 bf16 = 4 VGPRs (MFMA A/B frag)
typedef __attribute__((ext_vector_type(4))) float floatx4;  // MFMA C/D frag

#define TBH ((size_t)16777216)  // 32768*512 per-gate G stride (elements)

__device__ __forceinline__ float bfbits2f(unsigned short b) {
  return __uint_as_float(((unsigned int)b) << 16);
}
__device__ __forceinline__ unsigned short f2bf(float f) {
  unsigned int u = __float_as_uint(f);
  unsigned int r = (u + 0x7fffu + ((u >> 16) & 1u)) >> 16;  // RNE
  return (unsigned short)r;
}

// Relaxed device-scope atomics: sc-bit loads/stores that bypass the
// non-coherent per-XCD L2 path to the coherence point. NO acquire/release —
// those emit buffer_inv/buffer_wbl2 (full L2 flush) on gfx950 and were the
// 40us/round cost in R2. Ordering comes from __syncthreads()'s vmcnt(0)
// drain before the slot publish.
__device__ __forceinline__ void dev_store(unsigned int* p, unsigned int v) {
  __hip_atomic_store(p, v, __ATOMIC_RELAXED, __HIP_MEMORY_SCOPE_AGENT);
}
__device__ __forceinline__ unsigned int dev_load(const unsigned int* p) {
  return __hip_atomic_load(p, __ATOMIC_RELAXED, __HIP_MEMORY_SCOPE_AGENT);
}

// -------------------------------------------------------------------------
// prep: h0 (f32) -> hbuf32[0] (f32 bits); zero 512 slot ints; convert
// Whr/Whi/Whn to bf16 (Whb, 3*262144 elems).
// -------------------------------------------------------------------------
__global__ void prep_kernel(const float* __restrict__ h0,
                            unsigned int* __restrict__ hbuf32,
                            unsigned int* __restrict__ slots,
                            const float* __restrict__ Whr,
                            const float* __restrict__ Whi,
                            const float* __restrict__ Whn,
                            unsigned short* __restrict__ Whb) {
  int i = blockIdx.x * 256 + threadIdx.x;  // grid 1024*256 = 262144
  if (i < 64 * 512) hbuf32[i] = __float_as_uint(h0[i]);
  if (i < 512) slots[i] = 0;
#pragma unroll
  for (int rep = 0; rep < 3; ++rep) {
    int j = i + rep * 262144;
    float v = (j < 262144) ? Whr[j] : ((j < 524288) ? Whi[j - 262144] : Whn[j - 524288]);
    Whb[j] = f2bf(v);
  }
}

// -------------------------------------------------------------------------
// Phase 1: G[gate][t*64+b][n] = x@Wi^T + ctx@Wp^T + (bi+bh+bp)   (bf16 out)
// 128x128 tile, BK=32; f32 global -> bf16 LDS staging; 4 waves each 64x64.
// -------------------------------------------------------------------------
struct PreArgs {
  const float* x;
  const float* ctx;
  const float* Wi[3];
  const float* Wp[3];
  const float* bi[3];
  const float* bh[3];
  const float* bp[3];
  unsigned short* G;
};

__global__ __launch_bounds__(256) void gemm_pre(PreArgs args) {
  __shared__ short8 a_sm[512];  // [row(128)][sub(4)] : 128x32 bf16
  __shared__ short8 b_sm[512];
  const int tid = threadIdx.x;
  const int gate = blockIdx.z;
  const int n0 = blockIdx.x * 128;
  const int m0 = blockIdx.y * 128;
  const int wave = tid >> 6, lane = tid & 63;
  const int wm = (wave & 1) * 64, wn = (wave >> 1) * 64;
  const int lm = lane & 15, lq = lane >> 4;
  const float* Wi = args.Wi[gate];
  const float* Wp = args.Wp[gate];

  floatx4 acc[4][4];
#pragma unroll
  for (int i = 0; i < 4; ++i)
#pragma unroll
    for (int j = 0; j < 4; ++j) acc[i][j] = floatx4{0.f, 0.f, 0.f, 0.f};

  for (int kb = 0; kb < 32; ++kb) {
    const float* asrc = (kb < 16) ? args.x : args.ctx;
    const float* bsrc = (kb < 16) ? Wi : Wp;
    const int k0 = (kb & 15) * 32;
    __syncthreads();
#pragma unroll
    for (int c = 0; c < 2; ++c) {
      int s = c * 256 + tid;
      int row = s >> 2, sub = s & 3;
      const float* ap = asrc + (size_t)(m0 + row) * 512 + k0 + sub * 8;
      const float* bp = bsrc + (size_t)(n0 + row) * 512 + k0 + sub * 8;
      float4 a0 = *(const float4*)ap, a1 = *(const float4*)(ap + 4);
      float4 b0 = *(const float4*)bp, b1 = *(const float4*)(bp + 4);
      short8 av, bv;
      av[0] = (short)f2bf(a0.x); av[1] = (short)f2bf(a0.y);
      av[2] = (short)f2bf(a0.z); av[3] = (short)f2bf(a0.w);
      av[4] = (short)f2bf(a1.x); av[5] = (short)f2bf(a1.y);
      av[6] = (short)f2bf(a1.z); av[7] = (short)f2bf(a1.w);
      bv[0] = (short)f2bf(b0.x); bv[1] = (short)f2bf(b0.y);
      bv[2] = (short)f2bf(b0.z); bv[3] = (short)f2bf(b0.w);
      bv[4] = (short)f2bf(b1.x); bv[5] = (short)f2bf(b1.y);
      bv[6] = (short)f2bf(b1.z); bv[7] = (short)f2bf(b1.w);
      a_sm[row * 4 + sub] = av;
      b_sm[row * 4 + sub] = bv;
    }
    __syncthreads();
    short8 af[4], bf[4];
#pragma unroll
    for (int i = 0; i < 4; ++i) af[i] = a_sm[(wm + i * 16 + lm) * 4 + lq];
#pragma unroll
    for (int j = 0; j < 4; ++j) bf[j] = b_sm[(wn + j * 16 + lm) * 4 + lq];
#pragma unroll
    for (int i = 0; i < 4; ++i)
#pragma unroll
      for (int j = 0; j < 4; ++j)
        acc[i][j] = __builtin_amdgcn_mfma_f32_16x16x32_bf16(af[i], bf[j], acc[i][j], 0, 0, 0);
  }

  // epilogue: C/D layout col=lane&15, row=(lane>>4)*4+reg  [verified m89]
#pragma unroll
  for (int j = 0; j < 4; ++j) {
    int n = n0 + wn + j * 16 + lm;
    float bias = args.bi[gate][n] + args.bh[gate][n] + args.bp[gate][n];
#pragma unroll
    for (int i = 0; i < 4; ++i) {
      int mbase = m0 + wm + i * 16 + lq * 4;
#pragma unroll
      for (int r = 0; r < 4; ++r) {
        int m = mbase + r;            // m = b*512 + t (x row-major [B,T,D])
        int t = m & 511, b = m >> 9;  // G row = t*64 + b
        args.G[(size_t)gate * TBH + (size_t)(t * 64 + b) * 512 + n] = f2bf(acc[i][j][r] + bias);
      }
    }
  }
}

// -------------------------------------------------------------------------
// Recurrence: 256 persistent WGs = 8 batch-groups (8 batches) x 32 col-blocks
// (16 cols). W_h slices LDS-resident, fragment-packed. All cross-WG data via
// relaxed device-scope atomics; per-WG monotone slot counters for sync.
// -------------------------------------------------------------------------
__global__ __launch_bounds__(256, 1) void recur_kernel(
    const unsigned short* __restrict__ G,
    const unsigned short* __restrict__ Whb,   // [3][512][512] bf16
    unsigned int* __restrict__ hbuf32,        // [2][64][512] f32 bits
    unsigned int* __restrict__ rhpub,         // [64][512] bf16 bits in low16
    unsigned int* __restrict__ ipub,          // [64][512] bf16 bits in low16
    unsigned int* __restrict__ slotA,         // [8][32]
    unsigned int* __restrict__ slotB,         // [8][32]
    float* __restrict__ ys,                   // [64][512][512] f32
    float* __restrict__ hT) {                 // [64][512] f32
  __shared__ short8 w_sm[3 * 16 * 64];  // [gate][kb][lane] frag-packed: 48 KB
  __shared__ short8 hp_sm[16 * 64];     // h (phase A) then r*h (phase B): 16 KB

  const int tid = threadIdx.x;
  const int g = blockIdx.x & 7;    // batch group
  const int cb = blockIdx.x >> 3;  // col block 0..31
  const int b0 = g * 8;
  const int c0 = cb * 16;
  const int wave = tid >> 6, lane = tid & 63;
  const int lm = lane & 15, lq = lane >> 4;

  // ---- load weight slices once, fragment-packed (lane-sequential 16B) ----
#pragma unroll
  for (int gate = 0; gate < 3; ++gate) {
    const unsigned short* W = Whb + (size_t)gate * 262144;
    for (int s = tid; s < 1024; s += 256) {  // kb*64 + l
      int kb = s >> 6, l = s & 63;
      w_sm[gate * 1024 + s] =
          *(const short8*)(W + (size_t)(c0 + (l & 15)) * 512 + kb * 32 + (l >> 4) * 8);
    }
  }
  __syncthreads();

  for (int t = 0; t < 512; ++t) {
    const size_t inb = (size_t)(t & 1) * (64 * 512);
    const size_t outb = (size_t)((t + 1) & 1) * (64 * 512);

    // ---- prefetch operands that don't depend on this step's polls ----
    float gvA[4], hvv[4], gvB[4];
    if (wave < 2) {
#pragma unroll
      for (int r = 0; r < 4; ++r) {
        int b = lq * 4 + r;
        gvA[r] = 0.f;
        if (b < 8) {
          int gb = b0 + b, col = c0 + lm;
          gvA[r] = bfbits2f(G[(size_t)wave * TBH + (size_t)(t * 64 + gb) * 512 + col]);
        }
      }
    }
    if (wave == 0) {
#pragma unroll
      for (int r = 0; r < 4; ++r) {
        int b = lq * 4 + r;
        hvv[r] = 0.f;
        gvB[r] = 0.f;
        if (b < 8) {
          int gb = b0 + b, col = c0 + lm;
          hvv[r] = __uint_as_float(dev_load(&hbuf32[inb + (size_t)gb * 512 + col]));
          gvB[r] = bfbits2f(G[2 * TBH + (size_t)(t * 64 + gb) * 512 + col]);
        }
      }
    }

    // ---- stage h (f32 bits, device atomics -> bf16 frag-packed LDS) ----
    for (int s = tid; s < 1024; s += 256) {
      int l = s & 63;
      int m = l & 15;
      short8 v = {0, 0, 0, 0, 0, 0, 0, 0};
      if (m < 8) {
        const unsigned int* src = hbuf32 + inb + (size_t)(b0 + m) * 512 + (s >> 6) * 32 + (l >> 4) * 8;
#pragma unroll
        for (int j = 0; j < 8; ++j) v[j] = (short)f2bf(__uint_as_float(dev_load(src + j)));
      }
      hp_sm[s] = v;
    }
    __syncthreads();

    // ---- phase A: wave0 -> r gate (publishes r*h), wave1 -> i gate ----
    if (wave < 2) {
      floatx4 acc = {0.f, 0.f, 0.f, 0.f};
#pragma unroll
      for (int kb = 0; kb < 16; ++kb)
        acc = __builtin_amdgcn_mfma_f32_16x16x32_bf16(hp_sm[kb * 64 + lane],
                                                      w_sm[(wave * 16 + kb) * 64 + lane],
                                                      acc, 0, 0, 0);
#pragma unroll
      for (int r = 0; r < 4; ++r) {
        int b = lq * 4 + r;
        if (b < 8) {
          int gb = b0 + b, col = c0 + lm;
          float pre = acc[r] + gvA[r];
          float sv = 1.f / (1.f + __expf(-pre));
          if (wave == 0)
            dev_store(&rhpub[(size_t)gb * 512 + col], (unsigned int)f2bf(sv * hvv[r]));
          else
            dev_store(&ipub[(size_t)gb * 512 + col], (unsigned int)f2bf(sv));
        }
      }
    }
    __syncthreads();  // emits s_waitcnt vmcnt(0): write-through stores drained
    if (tid == 0) dev_store(&slotA[g * 32 + cb], (unsigned int)(t + 1));
    if (wave == 0) {
      bool done = lane >= 32;
      while (!__all(done)) {
        if (!done) done = dev_load(&slotA[g * 32 + lane]) >= (unsigned int)(t + 1);
      }
    }
    __syncthreads();

    // ---- load i, stage r*h (bf16 bits -> frag-packed LDS) ----
    float iv[4];
    if (wave == 0) {
#pragma unroll
      for (int r = 0; r < 4; ++r) {
        int b = lq * 4 + r;
        iv[r] = 0.f;
        if (b < 8)
          iv[r] = bfbits2f((unsigned short)dev_load(&ipub[(size_t)(b0 + b) * 512 + c0 + lm]));
      }
    }
    for (int s = tid; s < 1024; s += 256) {
      int l = s & 63;
      int m = l & 15;
      short8 v = {0, 0, 0, 0, 0, 0, 0, 0};
      if (m < 8) {
        const unsigned int* src = rhpub + (size_t)(b0 + m) * 512 + (s >> 6) * 32 + (l >> 4) * 8;
#pragma unroll
        for (int j = 0; j < 8; ++j) v[j] = (short)(unsigned short)dev_load(src + j);
      }
      hp_sm[s] = v;
    }
    __syncthreads();

    // ---- phase B: wave0 -> n gate + hy ----
    if (wave == 0) {
      floatx4 acc = {0.f, 0.f, 0.f, 0.f};
#pragma unroll
      for (int kb = 0; kb < 16; ++kb)
        acc = __builtin_amdgcn_mfma_f32_16x16x32_bf16(hp_sm[kb * 64 + lane],
                                                      w_sm[(2 * 16 + kb) * 64 + lane],
                                                      acc, 0, 0, 0);
#pragma unroll
      for (int r = 0; r < 4; ++r) {
        int b = lq * 4 + r;
        if (b < 8) {
          int gb = b0 + b, col = c0 + lm;
          float pre = acc[r] + gvB[r];
          float e = __expf(2.f * pre);
          float nv = 1.f - 2.f / (e + 1.f);  // tanh
          float hy = (1.f - iv[r]) * hvv[r] + iv[r] * nv;
          dev_store(&hbuf32[outb + (size_t)gb * 512 + col], __float_as_uint(hy));
          ys[((size_t)gb * 512 + (size_t)t) * 512 + col] = hy;
          if (t == 511) hT[(size_t)gb * 512 + col] = hy;
        }
      }
    }
    __syncthreads();  // drain wave0's h publish
    if (tid == 0) dev_store(&slotB[g * 32 + cb], (unsigned int)(t + 1));
    if (wave == 0) {
      bool done = lane >= 32;
      while (!__all(done)) {
        if (!done) done = dev_load(&slotB[g * 32 + lane]) >= (unsigned int)(t + 1);
      }
    }
    __syncthreads();
  }
}

// -------------------------------------------------------------------------
extern "C" void kernel_launch(void* const* d_in, const int* in_sizes, int n_in,
                              void* d_out, int out_size, void* d_ws, size_t ws_size,
                              hipStream_t stream) {
  typedef const float* cfp;
  cfp x = (cfp)d_in[0];
  cfp h0 = (cfp)d_in[1];
  cfp ctx = (cfp)d_in[2];

  PreArgs pa;
  pa.x = x;
  pa.ctx = ctx;
  for (int gi = 0; gi < 3; ++gi) {
    pa.Wi[gi] = (cfp)d_in[3 + 6 * gi];
    pa.bi[gi] = (cfp)d_in[4 + 6 * gi];
    pa.bh[gi] = (cfp)d_in[6 + 6 * gi];
    pa.Wp[gi] = (cfp)d_in[7 + 6 * gi];
    pa.bp[gi] = (cfp)d_in[8 + 6 * gi];
  }
  cfp Whr = (cfp)d_in[5], Whi = (cfp)d_in[11], Whn = (cfp)d_in[17];

  char* ws = (char*)d_ws;
  unsigned short* G = (unsigned short*)ws;          // 3 gates x 32 MB bf16
  size_t off = (size_t)3 * TBH * 2;                 // 100,663,296 B
  unsigned short* Whb = (unsigned short*)(ws + off);
  off += (size_t)3 * 262144 * 2;                    // 1,572,864 B
  unsigned int* hbuf32 = (unsigned int*)(ws + off);
  off += (size_t)2 * 64 * 512 * 4;
  unsigned int* rhpub = (unsigned int*)(ws + off);
  off += (size_t)64 * 512 * 4;
  unsigned int* ipub = (unsigned int*)(ws + off);
  off += (size_t)64 * 512 * 4;
  unsigned int* slotA = (unsigned int*)(ws + off);
  off += (size_t)256 * 4;
  unsigned int* slotB = (unsigned int*)(ws + off);
  off += (size_t)256 * 4;
  pa.G = G;

  float* out = (float*)d_out;
  float* ys = out;
  float* hT = out + (size_t)64 * 512 * 512;

  prep_kernel<<<1024, 256, 0, stream>>>(h0, hbuf32, slotA, Whr, Whi, Whn, Whb);
  dim3 gp(4, 256, 3);
  gemm_pre<<<gp, 256, 0, stream>>>(pa);
  recur_kernel<<<256, 256, 0, stream>>>(G, Whb, hbuf32, rhpub, ipub, slotA, slotB, ys, hT);
}